// Round 4
// baseline (87.689 us; speedup 1.0000x reference)
//
#include <hip/hip_runtime.h>
#include <hip/hip_bf16.h>
#include <math.h>

// DistWeightLoss on MI355X — round 4: 2-kernel graph, zero fixed overhead.
//
// ws layout: [0:N) pos_min f32 | [N:2N) row_sum f32 | [2N:3N) row_cnt f32
//            | +0 counter u32 (in pad) | Xbf bf16 [N][D]
//   A) pos_kernel: per-class 8x8 Gram (fp32, exact) + fused fp32->bf16 cvt,
//      exact JAX Threefry gumbel -> pos_min; ALSO zeroes row_sum/row_cnt
//      for its 8 rows and (block 0) the completion counter.
//   B) neg_panel_kernel: 256 blocks (1/CU), persistent 256-row A-panel x
//      1024-col j-chunk (8 double-buffered B-tiles, stage-before-compute).
//      8 waves x 64x64 MFMA out. Register mask-accum; one shfl-reduce +
//      2 atomics per row per block. Last block (device-scope ticket) runs
//      the final loss reduction with agent-scope atomic loads.

#define NN 8192
#define DD 128
#define KK 8
#define MARGIN 0.01f

#define BM 256
#define BN 128
#define JC 1024
#define JT (JC / BN)
#define NBLK ((NN / BM) * (NN / JC))  // 256

typedef __attribute__((ext_vector_type(8))) short short8;
typedef __attribute__((ext_vector_type(4))) float f32x4;

// ---------------- Threefry2x32 / JAX gumbel (bit-exact, validated) ----------------
__device__ __forceinline__ unsigned rotl32(unsigned x, unsigned r) {
    return (x << r) | (x >> (32u - r));
}

__device__ float gumbel_at(unsigned m) {
    const unsigned HALF = (NN * (KK - 1)) / 2;  // 28672
    unsigned c   = (m < HALF) ? m : (m - HALF);
    bool     hi  = (m >= HALF);
    const unsigned ks0 = 0u, ks1 = 42u;
    const unsigned ks2 = 0x1BD11BDAu ^ ks0 ^ ks1;
    unsigned x0 = c + ks0;
    unsigned x1 = (c + HALF) + ks1;
#define TF_ROUND(r) { x0 += x1; x1 = rotl32(x1, (r)); x1 ^= x0; }
    TF_ROUND(13) TF_ROUND(15) TF_ROUND(26) TF_ROUND(6)
    x0 += ks1; x1 += ks2 + 1u;
    TF_ROUND(17) TF_ROUND(29) TF_ROUND(16) TF_ROUND(24)
    x0 += ks2; x1 += ks0 + 2u;
    TF_ROUND(13) TF_ROUND(15) TF_ROUND(26) TF_ROUND(6)
    x0 += ks0; x1 += ks1 + 3u;
    TF_ROUND(17) TF_ROUND(29) TF_ROUND(16) TF_ROUND(24)
    x0 += ks1; x1 += ks2 + 4u;
    TF_ROUND(13) TF_ROUND(15) TF_ROUND(26) TF_ROUND(6)
    x0 += ks2; x1 += ks0 + 5u;
#undef TF_ROUND
    unsigned bits = hi ? x1 : x0;
    float f = __uint_as_float((bits >> 9) | 0x3f800000u) - 1.0f;
    float u = fmaxf(f, 1.17549435e-38f);
    return -logf(-logf(u));
}

// ---------------- fp32 -> bf16 (RNE) ----------------
__device__ __forceinline__ unsigned short bf16r(float f) {
    unsigned u = __float_as_uint(f);
    unsigned r = (u + 0x7FFFu + ((u >> 16) & 1u)) >> 16;
    return (unsigned short)r;
}

// ---------------- Kernel A: pos_min + cvt + zero-init ----------------
__global__ __launch_bounds__(64) void pos_kernel(const float* __restrict__ X,
                                                 float* __restrict__ pos_min,
                                                 float* __restrict__ row_sum,
                                                 float* __restrict__ row_cnt,
                                                 unsigned* __restrict__ counter,
                                                 unsigned short* __restrict__ Xbf) {
    __shared__ float Xc[KK * DD];
    __shared__ float gram[KK * KK];
    const int c   = blockIdx.x;
    const int tid = threadIdx.x;

    // zero-init the accumulators for this block's 8 rows (replaces memset)
    if (tid < KK) {
        row_sum[c * KK + tid] = 0.f;
        row_cnt[c * KK + tid] = 0.f;
    }
    if (c == 0 && tid == 63) *counter = 0u;

    const float4* src = (const float4*)(X + (size_t)c * KK * DD);
    float4*       dst = (float4*)Xc;
#pragma unroll
    for (int it = 0; it < (KK * DD / 4) / 64; ++it)
        dst[tid + it * 64] = src[tid + it * 64];
    __syncthreads();

    // fused cvt of this class's 8 rows (data already in LDS)
    ushort4* obf = (ushort4*)(Xbf + (size_t)c * KK * DD);
#pragma unroll
    for (int it = 0; it < 4; ++it) {
        int idx = tid + it * 64;
        float4 v = ((const float4*)Xc)[idx];
        ushort4 o;
        o.x = bf16r(v.x); o.y = bf16r(v.y); o.z = bf16r(v.z); o.w = bf16r(v.w);
        obf[idx] = o;
    }

    const int a = tid >> 3, b = tid & 7;
    float s = 0.f;
#pragma unroll
    for (int k = 0; k < DD; k += 4) {
        float4 va = *(const float4*)&Xc[a * DD + k];
        float4 vb = *(const float4*)&Xc[b * DD + k];
        s += va.x * vb.x + va.y * vb.y + va.z * vb.z + va.w * vb.w;
    }
    gram[a * KK + b] = s;
    __syncthreads();

    if (tid < KK) {
        const int r = tid;
        const int i = c * KK + r;
        float ps[KK - 1];
#pragma unroll
        for (int jj = 0; jj < KK - 1; ++jj)
            ps[jj] = gram[r * KK + ((r + 1 + jj) & (KK - 1))];
#pragma unroll
        for (int p = 0; p < KK - 2; ++p)
#pragma unroll
            for (int q = 0; q < KK - 2 - p; ++q) {
                float lo = fminf(ps[q], ps[q + 1]);
                float hi = fmaxf(ps[q], ps[q + 1]);
                ps[q] = lo; ps[q + 1] = hi;
            }
        float best = -1e30f;
        float pmin = ps[0];
#pragma unroll
        for (int jj = 0; jj < KK - 1; ++jj) {
            float g  = gumbel_at((unsigned)(i * (KK - 1) + jj));
            float sc = 5.0f * ps[jj] + g;
            if (sc > best) { best = sc; pmin = ps[jj]; }
        }
        pos_min[i] = pmin;
    }
}

// ---------------- async global->LDS 16B ----------------
__device__ __forceinline__ void async16(const void* g, void* l) {
    __builtin_amdgcn_global_load_lds(
        (const __attribute__((address_space(1))) unsigned int*)g,
        (__attribute__((address_space(3))) unsigned int*)l, 16, 0, 0);
}

// ---------------- Kernel B: panel MFMA + masked reduce + fused finalize ----------------
__global__ __launch_bounds__(512, 2) void neg_panel_kernel(const unsigned short* __restrict__ Xbf,
                                                           const float* __restrict__ pos_min,
                                                           float* __restrict__ row_sum,
                                                           float* __restrict__ row_cnt,
                                                           unsigned* __restrict__ counter,
                                                           float* __restrict__ out) {
    __shared__ unsigned short As[BM * DD];     // 64 KB
    __shared__ unsigned short Bs[2][BN * DD];  // 2 x 32 KB
    __shared__ unsigned ticket_s;
    __shared__ float red[512];
    const int tid  = threadIdx.x;
    const int lane = tid & 63;
    const int w    = tid >> 6;
    const int wr   = w >> 1;
    const int wc   = w & 1;
    const int l15  = lane & 15, l4 = lane >> 4;
    const int i0   = blockIdx.x * BM;
    const int jb   = blockIdx.y * JC;

    // ---- stage A panel once
#pragma unroll
    for (int it = 0; it < 8; ++it) {
        int ch  = w * 512 + it * 64 + lane;
        int row = ch >> 4, c4 = ch & 15, srcc = c4 ^ (row & 7);
        async16(Xbf + (((size_t)(i0 + row)) << 7) + srcc * 8,
                &As[(w * 512 + it * 64) * 8]);
    }
    // ---- stage B tile 0
#pragma unroll
    for (int it = 0; it < 4; ++it) {
        int ch  = w * 256 + it * 64 + lane;
        int row = ch >> 4, c4 = ch & 15, srcc = c4 ^ (row & 7);
        async16(Xbf + (((size_t)(jb + row)) << 7) + srcc * 8,
                &Bs[0][(w * 256 + it * 64) * 8]);
    }

    float thr[4][4];
    int   i3[4][4];
#pragma unroll
    for (int m = 0; m < 4; ++m)
#pragma unroll
        for (int r = 0; r < 4; ++r) {
            int i = i0 + wr * 64 + m * 16 + l4 * 4 + r;
            thr[m][r] = pos_min[i] - MARGIN;
            i3[m][r]  = i >> 3;
        }
    float s[4][4] = {{0.f}}, c[4][4] = {{0.f}};
    const bool diag = (jb < i0 + BM) && (i0 < jb + JC);

    __syncthreads();  // A + B0 resident

    for (int t = 0; t < JT; ++t) {
        if (t + 1 < JT) {
            const int jb2 = jb + (t + 1) * BN;
#pragma unroll
            for (int it = 0; it < 4; ++it) {
                int ch  = w * 256 + it * 64 + lane;
                int row = ch >> 4, c4 = ch & 15, srcc = c4 ^ (row & 7);
                async16(Xbf + (((size_t)(jb2 + row)) << 7) + srcc * 8,
                        &Bs[(t + 1) & 1][(w * 256 + it * 64) * 8]);
            }
        }
        const unsigned short* Bp = Bs[t & 1];

        f32x4 acc[4][4] = {};
#pragma unroll
        for (int kk = 0; kk < DD / 32; ++kk) {
            short8 a[4], b[4];
            const int kb = (kk * 32 + l4 * 8) * 2;
#pragma unroll
            for (int m = 0; m < 4; ++m) {
                int ra = wr * 64 + m * 16 + l15;
                a[m] = *(const short8*)((const char*)As + ((ra * 256 + kb) ^ ((ra & 7) << 4)));
                int rb = wc * 64 + m * 16 + l15;
                b[m] = *(const short8*)((const char*)Bp + ((rb * 256 + kb) ^ ((rb & 7) << 4)));
            }
#pragma unroll
            for (int m = 0; m < 4; ++m)
#pragma unroll
                for (int n = 0; n < 4; ++n)
                    acc[m][n] = __builtin_amdgcn_mfma_f32_16x16x32_bf16(a[m], b[n], acc[m][n], 0, 0, 0);
        }

        const int jcol = jb + t * BN + wc * 64 + l15;
        if (diag) {
#pragma unroll
            for (int n = 0; n < 4; ++n) {
                const int j3 = (jcol + n * 16) >> 3;
#pragma unroll
                for (int m = 0; m < 4; ++m)
#pragma unroll
                    for (int r = 0; r < 4; ++r) {
                        float v = acc[m][n][r];
                        bool k = (v > thr[m][r]) && (i3[m][r] != j3);
                        s[m][r] += k ? v : 0.f;
                        c[m][r] += k ? 1.f : 0.f;
                    }
            }
        } else {
#pragma unroll
            for (int n = 0; n < 4; ++n)
#pragma unroll
                for (int m = 0; m < 4; ++m)
#pragma unroll
                    for (int r = 0; r < 4; ++r) {
                        float v = acc[m][n][r];
                        bool k = (v > thr[m][r]);
                        s[m][r] += k ? v : 0.f;
                        c[m][r] += k ? 1.f : 0.f;
                    }
        }
        __syncthreads();
    }

    // ---- per-block: shfl-reduce + device atomics
#pragma unroll
    for (int m = 0; m < 4; ++m)
#pragma unroll
        for (int r = 0; r < 4; ++r) {
            float sv = s[m][r], cv = c[m][r];
#pragma unroll
            for (int off = 1; off < 16; off <<= 1) {
                sv += __shfl_xor(sv, off);
                cv += __shfl_xor(cv, off);
            }
            if (l15 == 0) {
                int i = i0 + wr * 64 + m * 16 + l4 * 4 + r;
                atomicAdd(&row_sum[i], sv);
                atomicAdd(&row_cnt[i], cv);
            }
        }

    // ---- last-block finalize (device-scope ticket; Guideline 16)
    __threadfence();
    __syncthreads();
    if (tid == 0)
        ticket_s = __hip_atomic_fetch_add(counter, 1u, __ATOMIC_ACQ_REL,
                                          __HIP_MEMORY_SCOPE_AGENT);
    __syncthreads();
    if (ticket_s == NBLK - 1) {
        __threadfence();
        float local = 0.f;
#pragma unroll
        for (int it = 0; it < NN / 512; ++it) {
            int i = tid + it * 512;
            float cnt = __hip_atomic_load(&row_cnt[i], __ATOMIC_RELAXED,
                                          __HIP_MEMORY_SCOPE_AGENT);
            if (cnt > 0.f) {
                float sm = __hip_atomic_load(&row_sum[i], __ATOMIC_RELAXED,
                                             __HIP_MEMORY_SCOPE_AGENT);
                local += sm / fmaxf(cnt, 1.0f) - pos_min[i] + MARGIN;
            }
        }
        red[tid] = local;
        __syncthreads();
        for (int st = 256; st > 0; st >>= 1) {
            if (tid < st) red[tid] += red[tid + st];
            __syncthreads();
        }
        if (tid == 0) out[0] = red[0] / (float)NN;
    }
}

extern "C" void kernel_launch(void* const* d_in, const int* in_sizes, int n_in,
                              void* d_out, int out_size, void* d_ws, size_t ws_size,
                              hipStream_t stream) {
    const float* X = (const float*)d_in[0];
    float*    pos_min = (float*)d_ws;
    float*    row_sum = pos_min + NN;
    float*    row_cnt = row_sum + NN;
    unsigned* counter = (unsigned*)((char*)d_ws + (size_t)3 * NN * 4);
    unsigned short* Xbf = (unsigned short*)((char*)d_ws + (size_t)3 * NN * 4 + 256);

    pos_kernel<<<NN / KK, 64, 0, stream>>>(X, pos_min, row_sum, row_cnt, counter, Xbf);
    dim3 grid(NN / BM, NN / JC);
    neg_panel_kernel<<<grid, 512, 0, stream>>>(Xbf, pos_min, row_sum, row_cnt,
                                               counter, (float*)d_out);
}

// Round 5
// 80.717 us; speedup vs baseline: 1.0864x; 1.0864x over previous
//
#include <hip/hip_runtime.h>
#include <hip/hip_bf16.h>
#include <math.h>

// DistWeightLoss on MI355X — round 5: 16-wave panel blocks (4 waves/SIMD),
// fused finalize REVERTED (round-4 regression), no memset node.
//
// ws layout: [0:N) pos_min f32 | [N:2N) row_sum f32 | [2N:3N) row_cnt f32
//            | [3N:) Xbf bf16 [N][D]
//   A) pos_kernel: per-class 8x8 Gram (fp32, exact) + fused fp32->bf16 cvt
//      + zero-init of row_sum/row_cnt (replaces memset node).
//   B) neg_panel_kernel: grid 32x8 = 256 blocks (1/CU). 1024 threads =
//      16 waves (4 wr x 4 wc), wave = 64x32 out of 16x16x32 bf16 MFMA.
//      BM=256 A-panel staged once (64 KB) + double-buffered BN=128 B-tiles
//      (2x32 KB) = 128 KB LDS. Register mask-accum across 8 steps; one
//      shfl-reduce + 2 atomics per row per block at the end.
//   C) finalize_kernel: separate, loss = sum(valid? s/c - pos + m : 0)/N.

#define NN 8192
#define DD 128
#define KK 8
#define MARGIN 0.01f

#define BM 256
#define BN 128
#define JC 1024
#define JT (JC / BN)  // 8

typedef __attribute__((ext_vector_type(8))) short short8;
typedef __attribute__((ext_vector_type(4))) float f32x4;

// ---------------- Threefry2x32 / JAX gumbel (bit-exact, validated) ----------------
__device__ __forceinline__ unsigned rotl32(unsigned x, unsigned r) {
    return (x << r) | (x >> (32u - r));
}

__device__ float gumbel_at(unsigned m) {
    const unsigned HALF = (NN * (KK - 1)) / 2;  // 28672
    unsigned c   = (m < HALF) ? m : (m - HALF);
    bool     hi  = (m >= HALF);
    const unsigned ks0 = 0u, ks1 = 42u;
    const unsigned ks2 = 0x1BD11BDAu ^ ks0 ^ ks1;
    unsigned x0 = c + ks0;
    unsigned x1 = (c + HALF) + ks1;
#define TF_ROUND(r) { x0 += x1; x1 = rotl32(x1, (r)); x1 ^= x0; }
    TF_ROUND(13) TF_ROUND(15) TF_ROUND(26) TF_ROUND(6)
    x0 += ks1; x1 += ks2 + 1u;
    TF_ROUND(17) TF_ROUND(29) TF_ROUND(16) TF_ROUND(24)
    x0 += ks2; x1 += ks0 + 2u;
    TF_ROUND(13) TF_ROUND(15) TF_ROUND(26) TF_ROUND(6)
    x0 += ks0; x1 += ks1 + 3u;
    TF_ROUND(17) TF_ROUND(29) TF_ROUND(16) TF_ROUND(24)
    x0 += ks1; x1 += ks2 + 4u;
    TF_ROUND(13) TF_ROUND(15) TF_ROUND(26) TF_ROUND(6)
    x0 += ks2; x1 += ks0 + 5u;
#undef TF_ROUND
    unsigned bits = hi ? x1 : x0;
    float f = __uint_as_float((bits >> 9) | 0x3f800000u) - 1.0f;
    float u = fmaxf(f, 1.17549435e-38f);
    return -logf(-logf(u));
}

// ---------------- fp32 -> bf16 (RNE) ----------------
__device__ __forceinline__ unsigned short bf16r(float f) {
    unsigned u = __float_as_uint(f);
    unsigned r = (u + 0x7FFFu + ((u >> 16) & 1u)) >> 16;
    return (unsigned short)r;
}

// ---------------- Kernel A: pos_min + cvt + zero-init ----------------
__global__ __launch_bounds__(64) void pos_kernel(const float* __restrict__ X,
                                                 float* __restrict__ pos_min,
                                                 float* __restrict__ row_sum,
                                                 float* __restrict__ row_cnt,
                                                 unsigned short* __restrict__ Xbf) {
    __shared__ float Xc[KK * DD];
    __shared__ float gram[KK * KK];
    const int c   = blockIdx.x;
    const int tid = threadIdx.x;

    if (tid < KK) {
        row_sum[c * KK + tid] = 0.f;
        row_cnt[c * KK + tid] = 0.f;
    }

    const float4* src = (const float4*)(X + (size_t)c * KK * DD);
    float4*       dst = (float4*)Xc;
#pragma unroll
    for (int it = 0; it < (KK * DD / 4) / 64; ++it)
        dst[tid + it * 64] = src[tid + it * 64];
    __syncthreads();

    ushort4* obf = (ushort4*)(Xbf + (size_t)c * KK * DD);
#pragma unroll
    for (int it = 0; it < 4; ++it) {
        int idx = tid + it * 64;
        float4 v = ((const float4*)Xc)[idx];
        ushort4 o;
        o.x = bf16r(v.x); o.y = bf16r(v.y); o.z = bf16r(v.z); o.w = bf16r(v.w);
        obf[idx] = o;
    }

    const int a = tid >> 3, b = tid & 7;
    float s = 0.f;
#pragma unroll
    for (int k = 0; k < DD; k += 4) {
        float4 va = *(const float4*)&Xc[a * DD + k];
        float4 vb = *(const float4*)&Xc[b * DD + k];
        s += va.x * vb.x + va.y * vb.y + va.z * vb.z + va.w * vb.w;
    }
    gram[a * KK + b] = s;
    __syncthreads();

    if (tid < KK) {
        const int r = tid;
        const int i = c * KK + r;
        float ps[KK - 1];
#pragma unroll
        for (int jj = 0; jj < KK - 1; ++jj)
            ps[jj] = gram[r * KK + ((r + 1 + jj) & (KK - 1))];
#pragma unroll
        for (int p = 0; p < KK - 2; ++p)
#pragma unroll
            for (int q = 0; q < KK - 2 - p; ++q) {
                float lo = fminf(ps[q], ps[q + 1]);
                float hi = fmaxf(ps[q], ps[q + 1]);
                ps[q] = lo; ps[q + 1] = hi;
            }
        float best = -1e30f;
        float pmin = ps[0];
#pragma unroll
        for (int jj = 0; jj < KK - 1; ++jj) {
            float g  = gumbel_at((unsigned)(i * (KK - 1) + jj));
            float sc = 5.0f * ps[jj] + g;
            if (sc > best) { best = sc; pmin = ps[jj]; }
        }
        pos_min[i] = pmin;
    }
}

// ---------------- async global->LDS 16B ----------------
__device__ __forceinline__ void async16(const void* g, void* l) {
    __builtin_amdgcn_global_load_lds(
        (const __attribute__((address_space(1))) unsigned int*)g,
        (__attribute__((address_space(3))) unsigned int*)l, 16, 0, 0);
}

// ---------------- Kernel B: 16-wave panel MFMA + masked reduce ----------------
// LDS rows = 128 bf16 = 256 B = 16 chunks of 16B. ds_read swizzle:
// byte ^= ((row&7)<<4); global_load_lds writes linearly so the SOURCE
// chunk index carries the same involution (rule #21).
__global__ __launch_bounds__(1024, 4) void neg_panel_kernel(const unsigned short* __restrict__ Xbf,
                                                            const float* __restrict__ pos_min,
                                                            float* __restrict__ row_sum,
                                                            float* __restrict__ row_cnt) {
    __shared__ unsigned short As[BM * DD];     // 64 KB
    __shared__ unsigned short Bs[2][BN * DD];  // 2 x 32 KB
    const int tid  = threadIdx.x;
    const int lane = tid & 63;
    const int w    = tid >> 6;      // 0..15
    const int wr   = w >> 2;        // 0..3 : 64-row band
    const int wc   = w & 3;         // 0..3 : 32-col band
    const int l15  = lane & 15, l4 = lane >> 4;
    const int i0   = blockIdx.x * BM;
    const int jb   = blockIdx.y * JC;

    // ---- stage A panel once: 4096 chunks, 4 per thread
#pragma unroll
    for (int it = 0; it < 4; ++it) {
        int ch  = it * 1024 + tid;
        int row = ch >> 4, c4 = ch & 15, srcc = c4 ^ (row & 7);
        async16(Xbf + (((size_t)(i0 + row)) << 7) + srcc * 8, &As[ch * 8]);
    }
    // ---- stage B tile 0: 2048 chunks, 2 per thread
#pragma unroll
    for (int it = 0; it < 2; ++it) {
        int ch  = it * 1024 + tid;
        int row = ch >> 4, c4 = ch & 15, srcc = c4 ^ (row & 7);
        async16(Xbf + (((size_t)(jb + row)) << 7) + srcc * 8, &Bs[0][ch * 8]);
    }

    // per-lane thresholds / class ids for the 16 rows this lane reduces
    float thr[4][4];
    int   i3[4];
#pragma unroll
    for (int m = 0; m < 4; ++m) {
        const int ib = i0 + wr * 64 + m * 16 + l4 * 4;
        i3[m] = ib >> 3;  // rows ib..ib+3 share one class (8-aligned blocks)
#pragma unroll
        for (int r = 0; r < 4; ++r) thr[m][r] = pos_min[ib + r] - MARGIN;
    }
    float s[4][4] = {{0.f}}, c[4][4] = {{0.f}};
    const bool diag = (jb < i0 + BM) && (i0 < jb + JC);

    __syncthreads();  // A + B0 resident

    for (int t = 0; t < JT; ++t) {
        if (t + 1 < JT) {
            const int jb2 = jb + (t + 1) * BN;
#pragma unroll
            for (int it = 0; it < 2; ++it) {
                int ch  = it * 1024 + tid;
                int row = ch >> 4, c4 = ch & 15, srcc = c4 ^ (row & 7);
                async16(Xbf + (((size_t)(jb2 + row)) << 7) + srcc * 8,
                        &Bs[(t + 1) & 1][ch * 8]);
            }
        }
        const unsigned short* Bp = Bs[t & 1];

        f32x4 acc[4][2] = {};
#pragma unroll
        for (int kk = 0; kk < DD / 32; ++kk) {
            short8 a[4], b[2];
            const int kb = (kk * 32 + l4 * 8) * 2;
#pragma unroll
            for (int m = 0; m < 4; ++m) {
                int ra = wr * 64 + m * 16 + l15;
                a[m] = *(const short8*)((const char*)As + ((ra * 256 + kb) ^ ((ra & 7) << 4)));
            }
#pragma unroll
            for (int n = 0; n < 2; ++n) {
                int rb = wc * 32 + n * 16 + l15;
                b[n] = *(const short8*)((const char*)Bp + ((rb * 256 + kb) ^ ((rb & 7) << 4)));
            }
#pragma unroll
            for (int m = 0; m < 4; ++m)
#pragma unroll
                for (int n = 0; n < 2; ++n)
                    acc[m][n] = __builtin_amdgcn_mfma_f32_16x16x32_bf16(a[m], b[n], acc[m][n], 0, 0, 0);
        }

        // mask-accumulate (C/D layout: col=lane&15, row=(lane>>4)*4+reg)
        const int jc0 = jb + t * BN + wc * 32 + l15;
        if (diag) {
#pragma unroll
            for (int n = 0; n < 2; ++n) {
                const int j3 = (jc0 + n * 16) >> 3;
#pragma unroll
                for (int m = 0; m < 4; ++m)
#pragma unroll
                    for (int r = 0; r < 4; ++r) {
                        float v = acc[m][n][r];
                        bool k = (v > thr[m][r]) && (i3[m] != j3);
                        s[m][r] += k ? v : 0.f;
                        c[m][r] += k ? 1.f : 0.f;
                    }
            }
        } else {
#pragma unroll
            for (int n = 0; n < 2; ++n)
#pragma unroll
                for (int m = 0; m < 4; ++m)
#pragma unroll
                    for (int r = 0; r < 4; ++r) {
                        float v = acc[m][n][r];
                        bool k = (v > thr[m][r]);
                        s[m][r] += k ? v : 0.f;
                        c[m][r] += k ? 1.f : 0.f;
                    }
        }
        __syncthreads();  // stage t+1 landed; all reads of Bs[t&1] done
    }

    // ---- once per block: reduce across the 16 col-lanes, then atomics
#pragma unroll
    for (int m = 0; m < 4; ++m)
#pragma unroll
        for (int r = 0; r < 4; ++r) {
            float sv = s[m][r], cv = c[m][r];
#pragma unroll
            for (int off = 1; off < 16; off <<= 1) {
                sv += __shfl_xor(sv, off);
                cv += __shfl_xor(cv, off);
            }
            if (l15 == 0) {
                int i = i0 + wr * 64 + m * 16 + l4 * 4 + r;
                atomicAdd(&row_sum[i], sv);
                atomicAdd(&row_cnt[i], cv);
            }
        }
}

// ---------------- Kernel C: finalize ----------------
__global__ __launch_bounds__(1024) void finalize_kernel(const float* __restrict__ row_sum,
                                                        const float* __restrict__ row_cnt,
                                                        const float* __restrict__ pos_min,
                                                        float* __restrict__ out) {
    __shared__ float red[1024];
    const int tid = threadIdx.x;
    float local = 0.f;
#pragma unroll
    for (int it = 0; it < NN / 1024; ++it) {
        int i = tid + it * 1024;
        float cnt = row_cnt[i];
        if (cnt > 0.f) {
            float nm = row_sum[i] / fmaxf(cnt, 1.0f);
            local += nm - pos_min[i] + MARGIN;
        }
    }
    red[tid] = local;
    __syncthreads();
    for (int st = 512; st > 0; st >>= 1) {
        if (tid < st) red[tid] += red[tid + st];
        __syncthreads();
    }
    if (tid == 0) out[0] = red[0] / (float)NN;
}

extern "C" void kernel_launch(void* const* d_in, const int* in_sizes, int n_in,
                              void* d_out, int out_size, void* d_ws, size_t ws_size,
                              hipStream_t stream) {
    const float* X = (const float*)d_in[0];
    float* pos_min = (float*)d_ws;
    float* row_sum = pos_min + NN;
    float* row_cnt = row_sum + NN;
    unsigned short* Xbf = (unsigned short*)((char*)d_ws + (size_t)3 * NN * 4);

    pos_kernel<<<NN / KK, 64, 0, stream>>>(X, pos_min, row_sum, row_cnt, Xbf);
    dim3 grid(NN / BM, NN / JC);
    neg_panel_kernel<<<grid, 1024, 0, stream>>>(Xbf, pos_min, row_sum, row_cnt);
    finalize_kernel<<<1, 1024, 0, stream>>>(row_sum, row_cnt, pos_min, (float*)d_out);
}

// Round 6
// 45.858 us; speedup vs baseline: 1.9122x; 1.7601x over previous
//
#include <hip/hip_runtime.h>
#include <hip/hip_bf16.h>
#include <math.h>

// DistWeightLoss on MI355X — round 6: A-panel in registers, 512-thread
// blocks, 2 independent blocks/CU (round-5 spilled: 1024-thr block got
// VGPR=64 and 71 MB scratch writes).
//
// ws layout: [0:N) pos_min f32 | [N:2N) row_sum f32 | [2N:3N) row_cnt f32
//            | [3N:) Xbf bf16 [N][D]
//   A) pos_kernel: per-class 8x8 Gram (fp32, exact) + fused fp32->bf16 cvt
//      + zero-init of row_sum/row_cnt.
//   B) neg_panel_kernel: grid 64x8 = 512 blocks (2/CU). 512 threads =
//      8 waves (4 row-bands x 2 col-bands). Wave = 32 rows x 32 cols of
//      16x16x32 bf16 MFMA. A-rows held in VGPRs for the whole j-stream
//      (areg[2][4], no A LDS). B: BN=64 double-buffered LDS (2x16 KB),
//      global_load_lds w/ pre-swizzled source. Register mask-accum;
//      shfl-reduce + 2 atomics per row per block at the end.
//   C) finalize_kernel: loss = sum(valid? s/c - pos + m : 0)/N.

#define NN 8192
#define DD 128
#define KK 8
#define MARGIN 0.01f

#define BM 128
#define BN 64
#define JC 1024
#define JT (JC / BN)  // 16

typedef __attribute__((ext_vector_type(8))) short short8;
typedef __attribute__((ext_vector_type(4))) float f32x4;

// ---------------- Threefry2x32 / JAX gumbel (bit-exact, validated) ----------------
__device__ __forceinline__ unsigned rotl32(unsigned x, unsigned r) {
    return (x << r) | (x >> (32u - r));
}

__device__ float gumbel_at(unsigned m) {
    const unsigned HALF = (NN * (KK - 1)) / 2;  // 28672
    unsigned c   = (m < HALF) ? m : (m - HALF);
    bool     hi  = (m >= HALF);
    const unsigned ks0 = 0u, ks1 = 42u;
    const unsigned ks2 = 0x1BD11BDAu ^ ks0 ^ ks1;
    unsigned x0 = c + ks0;
    unsigned x1 = (c + HALF) + ks1;
#define TF_ROUND(r) { x0 += x1; x1 = rotl32(x1, (r)); x1 ^= x0; }
    TF_ROUND(13) TF_ROUND(15) TF_ROUND(26) TF_ROUND(6)
    x0 += ks1; x1 += ks2 + 1u;
    TF_ROUND(17) TF_ROUND(29) TF_ROUND(16) TF_ROUND(24)
    x0 += ks2; x1 += ks0 + 2u;
    TF_ROUND(13) TF_ROUND(15) TF_ROUND(26) TF_ROUND(6)
    x0 += ks0; x1 += ks1 + 3u;
    TF_ROUND(17) TF_ROUND(29) TF_ROUND(16) TF_ROUND(24)
    x0 += ks1; x1 += ks2 + 4u;
    TF_ROUND(13) TF_ROUND(15) TF_ROUND(26) TF_ROUND(6)
    x0 += ks2; x1 += ks0 + 5u;
#undef TF_ROUND
    unsigned bits = hi ? x1 : x0;
    float f = __uint_as_float((bits >> 9) | 0x3f800000u) - 1.0f;
    float u = fmaxf(f, 1.17549435e-38f);
    return -logf(-logf(u));
}

// ---------------- fp32 -> bf16 (RNE) ----------------
__device__ __forceinline__ unsigned short bf16r(float f) {
    unsigned u = __float_as_uint(f);
    unsigned r = (u + 0x7FFFu + ((u >> 16) & 1u)) >> 16;
    return (unsigned short)r;
}

// ---------------- Kernel A: pos_min + cvt + zero-init ----------------
__global__ __launch_bounds__(64) void pos_kernel(const float* __restrict__ X,
                                                 float* __restrict__ pos_min,
                                                 float* __restrict__ row_sum,
                                                 float* __restrict__ row_cnt,
                                                 unsigned short* __restrict__ Xbf) {
    __shared__ float Xc[KK * DD];
    __shared__ float gram[KK * KK];
    const int c   = blockIdx.x;
    const int tid = threadIdx.x;

    if (tid < KK) {
        row_sum[c * KK + tid] = 0.f;
        row_cnt[c * KK + tid] = 0.f;
    }

    const float4* src = (const float4*)(X + (size_t)c * KK * DD);
    float4*       dst = (float4*)Xc;
#pragma unroll
    for (int it = 0; it < (KK * DD / 4) / 64; ++it)
        dst[tid + it * 64] = src[tid + it * 64];
    __syncthreads();

    ushort4* obf = (ushort4*)(Xbf + (size_t)c * KK * DD);
#pragma unroll
    for (int it = 0; it < 4; ++it) {
        int idx = tid + it * 64;
        float4 v = ((const float4*)Xc)[idx];
        ushort4 o;
        o.x = bf16r(v.x); o.y = bf16r(v.y); o.z = bf16r(v.z); o.w = bf16r(v.w);
        obf[idx] = o;
    }

    const int a = tid >> 3, b = tid & 7;
    float s = 0.f;
#pragma unroll
    for (int k = 0; k < DD; k += 4) {
        float4 va = *(const float4*)&Xc[a * DD + k];
        float4 vb = *(const float4*)&Xc[b * DD + k];
        s += va.x * vb.x + va.y * vb.y + va.z * vb.z + va.w * vb.w;
    }
    gram[a * KK + b] = s;
    __syncthreads();

    if (tid < KK) {
        const int r = tid;
        const int i = c * KK + r;
        float ps[KK - 1];
#pragma unroll
        for (int jj = 0; jj < KK - 1; ++jj)
            ps[jj] = gram[r * KK + ((r + 1 + jj) & (KK - 1))];
#pragma unroll
        for (int p = 0; p < KK - 2; ++p)
#pragma unroll
            for (int q = 0; q < KK - 2 - p; ++q) {
                float lo = fminf(ps[q], ps[q + 1]);
                float hi = fmaxf(ps[q], ps[q + 1]);
                ps[q] = lo; ps[q + 1] = hi;
            }
        float best = -1e30f;
        float pmin = ps[0];
#pragma unroll
        for (int jj = 0; jj < KK - 1; ++jj) {
            float g  = gumbel_at((unsigned)(i * (KK - 1) + jj));
            float sc = 5.0f * ps[jj] + g;
            if (sc > best) { best = sc; pmin = ps[jj]; }
        }
        pos_min[i] = pmin;
    }
}

// ---------------- async global->LDS 16B ----------------
__device__ __forceinline__ void async16(const void* g, void* l) {
    __builtin_amdgcn_global_load_lds(
        (const __attribute__((address_space(1))) unsigned int*)g,
        (__attribute__((address_space(3))) unsigned int*)l, 16, 0, 0);
}

// ---------------- Kernel B: A-in-reg panel MFMA + masked reduce ----------------
// B LDS rows = 128 bf16 = 256 B = 16 chunks of 16B. ds_read swizzle:
// byte ^= ((row&7)<<4); global_load_lds writes linearly so the SOURCE
// chunk index carries the same involution (rule #21).
__global__ __launch_bounds__(512, 4) void neg_panel_kernel(const unsigned short* __restrict__ Xbf,
                                                           const float* __restrict__ pos_min,
                                                           float* __restrict__ row_sum,
                                                           float* __restrict__ row_cnt) {
    __shared__ unsigned short Bs[2][BN * DD];  // 2 x 16 KB
    const int tid  = threadIdx.x;
    const int lane = tid & 63;
    const int w    = tid >> 6;      // 0..7
    const int wr   = w >> 1;        // 0..3 : 32-row band
    const int wc   = w & 1;         // 0..1 : 32-col band
    const int l15  = lane & 15, l4 = lane >> 4;
    const int i0   = blockIdx.x * BM;
    const int jb   = blockIdx.y * JC;

    // ---- stage B tile 0: 1024 chunks, 2 per thread
#pragma unroll
    for (int it = 0; it < 2; ++it) {
        int ch  = it * 512 + tid;
        int row = ch >> 4, c4 = ch & 15, srcc = c4 ^ (row & 7);
        async16(Xbf + (((size_t)(jb + row)) << 7) + srcc * 8, &Bs[0][ch * 8]);
    }

    // ---- A fragments -> registers, held for the whole j-stream.
    // A-frag layout for mfma_16x16x32: lane reads row (16-block + l15),
    // k-slice l4*8 within each 32-wide kk block.
    short8 areg[2][4];
#pragma unroll
    for (int m = 0; m < 2; ++m) {
        const int row = i0 + wr * 32 + m * 16 + l15;
#pragma unroll
        for (int kk = 0; kk < 4; ++kk)
            areg[m][kk] = *(const short8*)(Xbf + (((size_t)row) << 7) + kk * 32 + l4 * 8);
    }

    // per-lane thresholds / class ids for the 8 rows this lane reduces
    float thr[2][4];
    int   i3[2];
#pragma unroll
    for (int m = 0; m < 2; ++m) {
        const int ib = i0 + wr * 32 + m * 16 + l4 * 4;
        i3[m] = ib >> 3;  // rows ib..ib+3 share one class (4-row reg block, 8-aligned)
#pragma unroll
        for (int r = 0; r < 4; ++r) thr[m][r] = pos_min[ib + r] - MARGIN;
    }
    float s[2][4] = {{0.f}}, c[2][4] = {{0.f}};

    __syncthreads();  // B0 resident (barrier drains vmcnt)

    for (int t = 0; t < JT; ++t) {
        if (t + 1 < JT) {
            const int jb2 = jb + (t + 1) * BN;
#pragma unroll
            for (int it = 0; it < 2; ++it) {
                int ch  = it * 512 + tid;
                int row = ch >> 4, c4 = ch & 15, srcc = c4 ^ (row & 7);
                async16(Xbf + (((size_t)(jb2 + row)) << 7) + srcc * 8,
                        &Bs[(t + 1) & 1][ch * 8]);
            }
        }
        const unsigned short* Bp = Bs[t & 1];

        f32x4 acc[2][2] = {};
#pragma unroll
        for (int kk = 0; kk < DD / 32; ++kk) {
            short8 b[2];
            const int kb = (kk * 32 + l4 * 8) * 2;
#pragma unroll
            for (int n = 0; n < 2; ++n) {
                int rb = wc * 32 + n * 16 + l15;
                b[n] = *(const short8*)((const char*)Bp + ((rb * 256 + kb) ^ ((rb & 7) << 4)));
            }
#pragma unroll
            for (int m = 0; m < 2; ++m)
#pragma unroll
                for (int n = 0; n < 2; ++n)
                    acc[m][n] = __builtin_amdgcn_mfma_f32_16x16x32_bf16(areg[m][kk], b[n], acc[m][n], 0, 0, 0);
        }

        // mask-accumulate (C/D layout: col=lane&15, row=(lane>>4)*4+reg)
        const int jt0  = jb + t * BN;
        const int jc0  = jt0 + wc * 32 + l15;
        const bool sdiag = (jt0 < i0 + BM) && (i0 < jt0 + BN);
        if (sdiag) {
#pragma unroll
            for (int n = 0; n < 2; ++n) {
                const int j3 = (jc0 + n * 16) >> 3;
#pragma unroll
                for (int m = 0; m < 2; ++m)
#pragma unroll
                    for (int r = 0; r < 4; ++r) {
                        float v = acc[m][n][r];
                        bool k = (v > thr[m][r]) && (i3[m] != j3);
                        s[m][r] += k ? v : 0.f;
                        c[m][r] += k ? 1.f : 0.f;
                    }
            }
        } else {
#pragma unroll
            for (int n = 0; n < 2; ++n)
#pragma unroll
                for (int m = 0; m < 2; ++m)
#pragma unroll
                    for (int r = 0; r < 4; ++r) {
                        float v = acc[m][n][r];
                        bool k = (v > thr[m][r]);
                        s[m][r] += k ? v : 0.f;
                        c[m][r] += k ? 1.f : 0.f;
                    }
        }
        __syncthreads();  // stage t+1 landed; all reads of Bs[t&1] done
    }

    // ---- once per block: reduce across the 16 col-lanes, then atomics
#pragma unroll
    for (int m = 0; m < 2; ++m)
#pragma unroll
        for (int r = 0; r < 4; ++r) {
            float sv = s[m][r], cv = c[m][r];
#pragma unroll
            for (int off = 1; off < 16; off <<= 1) {
                sv += __shfl_xor(sv, off);
                cv += __shfl_xor(cv, off);
            }
            if (l15 == 0) {
                int i = i0 + wr * 32 + m * 16 + l4 * 4 + r;
                atomicAdd(&row_sum[i], sv);
                atomicAdd(&row_cnt[i], cv);
            }
        }
}

// ---------------- Kernel C: finalize ----------------
__global__ __launch_bounds__(1024) void finalize_kernel(const float* __restrict__ row_sum,
                                                        const float* __restrict__ row_cnt,
                                                        const float* __restrict__ pos_min,
                                                        float* __restrict__ out) {
    __shared__ float red[1024];
    const int tid = threadIdx.x;
    float local = 0.f;
#pragma unroll
    for (int it = 0; it < NN / 1024; ++it) {
        int i = tid + it * 1024;
        float cnt = row_cnt[i];
        if (cnt > 0.f) {
            float nm = row_sum[i] / fmaxf(cnt, 1.0f);
            local += nm - pos_min[i] + MARGIN;
        }
    }
    red[tid] = local;
    __syncthreads();
    for (int st = 512; st > 0; st >>= 1) {
        if (tid < st) red[tid] += red[tid + st];
        __syncthreads();
    }
    if (tid == 0) out[0] = red[0] / (float)NN;
}

extern "C" void kernel_launch(void* const* d_in, const int* in_sizes, int n_in,
                              void* d_out, int out_size, void* d_ws, size_t ws_size,
                              hipStream_t stream) {
    const float* X = (const float*)d_in[0];
    float* pos_min = (float*)d_ws;
    float* row_sum = pos_min + NN;
    float* row_cnt = row_sum + NN;
    unsigned short* Xbf = (unsigned short*)((char*)d_ws + (size_t)3 * NN * 4);

    pos_kernel<<<NN / KK, 64, 0, stream>>>(X, pos_min, row_sum, row_cnt, Xbf);
    dim3 grid(NN / BM, NN / JC);
    neg_panel_kernel<<<grid, 512, 0, stream>>>(Xbf, pos_min, row_sum, row_cnt);
    finalize_kernel<<<1, 1024, 0, stream>>>(row_sum, row_cnt, pos_min, (float*)d_out);
}